// Round 14
// baseline (3698.305 us; speedup 1.0000x reference)
//
#include <hip/hip_runtime.h>
#include <hip/hip_bf16.h>
#include <cstdint>
#include <math.h>

// ---------------------------------------------------------------------------
// GMemLinear: out = (x @ W^T) + bias, W = jax.random.normal(key(seed),[N,K],f64)
// R14 = R12 (proven) + anti-phase wave schedule ONLY.
// R13 bug: global_load_lds builtin's imm offset applies to BOTH global and
// LDS addresses -> staged subtiles rotated -> NaN. Fix: offset stays 0,
// full global address computed per call (R12's exact STAGE).
// Anti-phase: waves wr=0 run clusters [c0,c4]; wr=1 run [c4,c0] with
// mirrored prefetch issue order, so the 2 waves/SIMD alternate matrix-pipe
// feeding instead of lockstep. Barrier/vmcnt structure identical to R12.
// ---------------------------------------------------------------------------

typedef __bf16  bf16x8 __attribute__((ext_vector_type(8)));
typedef float   f32x4  __attribute__((ext_vector_type(4)));
typedef unsigned short u16x8 __attribute__((ext_vector_type(8)));

__device__ __forceinline__ unsigned short f2bf_rne(float f) {
  uint32_t x = __float_as_uint(f);
  uint32_t r = (x + 0x7FFFu + ((x >> 16) & 1u)) >> 16;
  return (unsigned short)r;
}

// Threefry-2x32, 20 rounds (Random123 / JAX).
__device__ __forceinline__ void threefry2x32(uint32_t k0, uint32_t k1,
                                             uint32_t x0, uint32_t x1,
                                             uint32_t& o0, uint32_t& o1) {
  uint32_t ks0 = k0, ks1 = k1, ks2 = k0 ^ k1 ^ 0x1BD11BDAu;
  uint32_t ks[3] = {ks0, ks1, ks2};
  x0 += ks0; x1 += ks1;
  const uint32_t rot0[4] = {13u, 15u, 26u, 6u};
  const uint32_t rot1[4] = {17u, 29u, 16u, 24u};
#pragma unroll
  for (int i = 0; i < 5; ++i) {
    const uint32_t* r = (i & 1) ? rot1 : rot0;
#pragma unroll
    for (int j = 0; j < 4; ++j) {
      x0 += x1;
      x1 = (x1 << r[j]) | (x1 >> (32u - r[j]));
      x1 ^= x0;
    }
    x0 += ks[(i + 1) % 3];
    x1 += ks[(i + 2) % 3] + (uint32_t)(i + 1);
  }
  o0 = x0; o1 = x1;
}

__device__ __forceinline__ double erfinv_mixed(double u) {
  double au = fabs(u);
  double t  = (1.0 - au) * (1.0 + au);
  float  wf = -logf((float)t);
  if (wf < 15.5f) {
    float w, p;
    if (wf < 5.0f) {
      w = wf - 2.5f;
      p = 2.81022636e-08f;
      p = 3.43273939e-07f + p * w;
      p = -3.5233877e-06f + p * w;
      p = -4.39150654e-06f + p * w;
      p = 0.00021858087f + p * w;
      p = -0.00125372503f + p * w;
      p = -0.00417768164f + p * w;
      p = 0.246640727f + p * w;
      p = 1.50140941f + p * w;
    } else {
      w = sqrtf(wf) - 3.0f;
      p = -0.000200214257f;
      p = 0.000100950558f + p * w;
      p = 0.00134934322f + p * w;
      p = -0.00367342844f + p * w;
      p = 0.00573950773f + p * w;
      p = -0.0076224613f + p * w;
      p = 0.00943887047f + p * w;
      p = 1.00167406f + p * w;
      p = 2.83297682f + p * w;
    }
    return (double)(p * (float)u);
  } else {
    double L = -log(1.0 - au);
    double r = sqrt(L);
    r = sqrt(L - log(r) - 0.5723649429247001);
    r = sqrt(L - log(r) - 0.5723649429247001);
    return (u < 0.0) ? -r : r;
  }
}

// ---------------------------------------------------------------------------
// Fused pre-kernel: (bid&3)==0 blocks cast x f32->bf16; others regenerate W.
// ---------------------------------------------------------------------------
__global__ void gen_and_cast(const float* __restrict__ X,
                             unsigned short* __restrict__ Y,
                             unsigned short* __restrict__ W,
                             const int* __restrict__ seedp,
                             int nx, int nw) {
  const int tid = (int)threadIdx.x;
  const int bid = (int)blockIdx.x;
  if ((bid & 3) == 0) {
    const int n8 = nx >> 3;
    const int stride = 2048 * 256;
    for (int q = (int)((bid >> 2) * 256 + tid); q < n8; q += stride) {
      const float4* p = (const float4*)(X + ((size_t)q << 3));
      float4 a = p[0], b = p[1];
      u16x8 o;
      o[0] = f2bf_rne(a.x); o[1] = f2bf_rne(a.y);
      o[2] = f2bf_rne(a.z); o[3] = f2bf_rne(a.w);
      o[4] = f2bf_rne(b.x); o[5] = f2bf_rne(b.y);
      o[6] = f2bf_rne(b.z); o[7] = f2bf_rne(b.w);
      *(u16x8*)(Y + ((size_t)q << 3)) = o;
    }
  } else {
    const uint32_t k1 = (uint32_t)seedp[0];
    const uint32_t k0 = 0u;
    const double DLO = -0x1.fffffffffffffp-1;   // -(1 - 2^-53)
    const int nq = nw >> 2;
    const int gidx = bid - (bid >> 2) - 1;      // 0..6143 over non-cast blocks
    const int stride = 6144 * 256;
    for (int q = gidx * 256 + tid; q < nq; q += stride) {
      ushort4 outv;
      unsigned short tmp[4];
#pragma unroll
      for (int j = 0; j < 4; ++j) {
        uint32_t e = ((uint32_t)q << 2) + (uint32_t)j;
        uint32_t o0, o1;
        threefry2x32(k0, k1, 0u, e, o0, o1);
        uint64_t bits = ((uint64_t)o0 << 32) | (uint64_t)o1;
        uint64_t fb = (bits >> 12) | 0x3FF0000000000000ull;
        union { uint64_t u; double d; } cv; cv.u = fb;
        double f = cv.d - 1.0;
        double u = f * 2.0 + DLO;
        u = fmax(u, DLO);
        double x = erfinv_mixed(u);
        float wv = (float)(1.4142135623730951 * x);
        tmp[j] = f2bf_rne(wv);
      }
      outv.x = tmp[0]; outv.y = tmp[1]; outv.z = tmp[2]; outv.w = tmp[3];
      *(ushort4*)(W + ((size_t)q << 2)) = outv;
    }
  }
}

// ---------------------------------------------------------------------------
// 256x256 GEMM, BK=32, quad-buffer, anti-phase split prefetch.
// Even (wr=0) per tile, issue order A03',B',A47' -> entry lgkm(4) retires
//   A03+B (cluster c0's needs).
// Odd  (wr=1) per tile, issue order A47',B',A03' -> entry lgkm(4) retires
//   A47+B (cluster c4's needs).
// Ledger (both parities, DS in-order): entry 12 outstanding -> lgkm(4)
// retires 8; mid: +4 issued -> 8 outstanding -> lgkm(4) retires old 4;
// end: +8 issued -> 12. vmcnt(4)/barrier structure = R12 (proven race-free).
// ---------------------------------------------------------------------------

__device__ __forceinline__ void gload_lds16(const void* g, void* l) {
  __builtin_amdgcn_global_load_lds(
      (const __attribute__((address_space(1))) unsigned int*)g,
      (__attribute__((address_space(3))) unsigned int*)l, 16, 0, 0);
}

__device__ __forceinline__ uint32_t lds_u32(void* p) {
  return (uint32_t)(uintptr_t)(__attribute__((address_space(3))) char*)p;
}

template <int OFF>
__device__ __forceinline__ bf16x8 dsr16(uint32_t a) {
  bf16x8 r;
  asm volatile("ds_read_b128 %0, %1 offset:%2" : "=v"(r) : "v"(a), "i"(OFF));
  return r;
}

__global__ __launch_bounds__(512, 2) void gemm256(
    const unsigned short* __restrict__ A,   // [M][K] bf16
    const unsigned short* __restrict__ B,   // [N][K] bf16
    const float* __restrict__ bias,         // [N]
    float* __restrict__ C,                  // [M][N] f32
    int M, int N, int K) {
  __shared__ __align__(1024) char lds[131072];

  const int nwg = (int)gridDim.x;
  int wg = (int)blockIdx.x;
  wg = (wg & 7) * (nwg >> 3) + (wg >> 3);       // bijective: nwg % 8 == 0
  const int ntn = N >> 8;
  const int tm = wg / ntn, tn = wg - tm * ntn;

  const int tid = (int)threadIdx.x;
  const int w = tid >> 6, l = tid & 63;
  const int wr = w >> 2, wc = w & 3;            // wave grid 2(M) x 4(N)
  const int l15 = l & 15;

  // read-side swizzled lane offset within a 1KiB (16row x 64B) subtile
  int laneRd = (l15 << 6) | ((l >> 4) << 4);
  laneRd ^= ((l15 >> 1) & 3) << 4;
  // stage-side: lane l sources global row l>>2, col-slot pre-inverse-swizzled
  const int stRow = l >> 2;
  const int stCol = (((l & 3) ^ ((l >> 3) & 3)) << 4);

  const char* Ag = (const char*)A;
  const char* Bg = (const char*)B;
  const long rowA0 = (long)tm * 256;
  const long rowB0 = (long)tn * 256;
  const long Kb = (long)K;

  const uint32_t lds0  = lds_u32(&lds[0]);
  const uint32_t aBase = lds0 + (uint32_t)(wr * 8192 + laneRd);
  const uint32_t bBase = lds0 + 16384u + (uint32_t)(wc * 4096 + laneRd);

  // stage 2 subtiles (u = w*2, w*2+1) of tile kt_ into buffer cs_  (R12 exact)
#define STAGE_A(kt_, cs_)                                                     \
  _Pragma("unroll")                                                           \
  for (int i_ = 0; i_ < 2; ++i_) {                                            \
    const int u_ = w * 2 + i_;                                                \
    gload_lds16(Ag + 2 * ((rowA0 + u_ * 16 + stRow) * Kb + (long)(kt_) * 32) + stCol, \
                &lds[(cs_) * 32768 + u_ * 1024]);                             \
  }
#define STAGE_B(kt_, cs_)                                                     \
  _Pragma("unroll")                                                           \
  for (int i_ = 0; i_ < 2; ++i_) {                                            \
    const int u_ = w * 2 + i_;                                                \
    gload_lds16(Bg + 2 * ((rowB0 + u_ * 16 + stRow) * Kb + (long)(kt_) * 32) + stCol, \
                &lds[(cs_) * 32768 + 16384 + u_ * 1024]);                     \
  }

#define PF_A03(cn_)                                                           \
  {                                                                           \
    const uint32_t aB = aBase + (cn_) * 32768u;                               \
    aq[0] = dsr16<0>(aB);    aq[1] = dsr16<1024>(aB);                         \
    aq[2] = dsr16<2048>(aB); aq[3] = dsr16<3072>(aB);                         \
  }
#define PF_A47(cn_)                                                           \
  {                                                                           \
    const uint32_t aB = aBase + (cn_) * 32768u;                               \
    aq[4] = dsr16<4096>(aB); aq[5] = dsr16<5120>(aB);                         \
    aq[6] = dsr16<6144>(aB); aq[7] = dsr16<7168>(aB);                         \
  }
#define PF_B(cn_)                                                             \
  {                                                                           \
    const uint32_t bB = bBase + (cn_) * 32768u;                               \
    bq[0] = dsr16<0>(bB);    bq[1] = dsr16<1024>(bB);                         \
    bq[2] = dsr16<2048>(bB); bq[3] = dsr16<3072>(bB);                         \
  }

#define MFMA16(base_)                                                         \
  _Pragma("unroll")                                                           \
  for (int mi = 0; mi < 4; ++mi)                                              \
    _Pragma("unroll")                                                         \
    for (int ni = 0; ni < 4; ++ni)                                            \
      acc[(base_) + mi][ni] = __builtin_amdgcn_mfma_f32_16x16x32_bf16(        \
          aq[(base_) + mi], bq[ni], acc[(base_) + mi][ni], 0, 0, 0);

#define LGKM4 asm volatile("s_waitcnt lgkmcnt(4)" ::: "memory");              \
  __builtin_amdgcn_sched_barrier(0);
#define LGKM0 asm volatile("s_waitcnt lgkmcnt(0)" ::: "memory");              \
  __builtin_amdgcn_sched_barrier(0);

// One BK=32 tile. Entry invariant: this tile's 12 ds_reads already issued
// in this parity's order (even: A03,B,A47; odd: A47,B,A03).
#define TILE_BODY(c_, kt_, vm_, st_, pf_)                                     \
  {                                                                           \
    if (wr == 0) {                                                            \
      LGKM4                                                                   \
      __builtin_amdgcn_s_setprio(1);                                          \
      MFMA16(0)                                                               \
      __builtin_amdgcn_s_setprio(0);                                          \
      if (pf_) { PF_A03(((c_) + 1) & 3) }                                     \
      if (st_) { STAGE_A((kt_) + 3, ((c_) + 3) & 3) }                         \
      if (pf_) { LGKM4 } else { LGKM0 }                                       \
      __builtin_amdgcn_s_setprio(1);                                          \
      MFMA16(4)                                                               \
      __builtin_amdgcn_s_setprio(0);                                          \
      if (pf_) { PF_B(((c_) + 1) & 3) PF_A47(((c_) + 1) & 3) }                \
      if (st_) { STAGE_B((kt_) + 3, ((c_) + 3) & 3) }                         \
    } else {                                                                  \
      LGKM4                                                                   \
      __builtin_amdgcn_s_setprio(1);                                          \
      MFMA16(4)                                                               \
      __builtin_amdgcn_s_setprio(0);                                          \
      if (pf_) { PF_A47(((c_) + 1) & 3) }                                     \
      if (st_) { STAGE_A((kt_) + 3, ((c_) + 3) & 3) }                         \
      if (pf_) { LGKM4 } else { LGKM0 }                                       \
      __builtin_amdgcn_s_setprio(1);                                          \
      MFMA16(0)                                                               \
      __builtin_amdgcn_s_setprio(0);                                          \
      if (pf_) { PF_B(((c_) + 1) & 3) PF_A03(((c_) + 1) & 3) }                \
      if (st_) { STAGE_B((kt_) + 3, ((c_) + 3) & 3) }                         \
    }                                                                         \
    asm volatile("s_waitcnt vmcnt(" #vm_ ")" ::: "memory");                   \
    __builtin_amdgcn_sched_barrier(0);                                        \
    __builtin_amdgcn_s_barrier();                                             \
  }

  f32x4 acc[8][4];
#pragma unroll
  for (int i = 0; i < 8; ++i)
#pragma unroll
    for (int j = 0; j < 4; ++j) acc[i][j] = (f32x4){0.f, 0.f, 0.f, 0.f};

  bf16x8 aq[8], bq[4];

  const int NTt = K >> 5;   // 128 K-tiles of BK=32

  // prologue: stage tiles 0,1,2 into buffers 0,1,2; vmcnt(4) retires tiles
  // 0 AND 1; barrier; then tile-0 reads in each parity's steady-state order.
  STAGE_A(0, 0) STAGE_B(0, 0)
  STAGE_A(1, 1) STAGE_B(1, 1)
  STAGE_A(2, 2) STAGE_B(2, 2)
  asm volatile("s_waitcnt vmcnt(4)" ::: "memory");
  __builtin_amdgcn_sched_barrier(0);
  __builtin_amdgcn_s_barrier();
  if (wr == 0) { PF_A03(0) PF_B(0) PF_A47(0) }
  else         { PF_A47(0) PF_B(0) PF_A03(0) }

  int kt = 0;
  for (; kt + 7 < NTt; kt += 4) {
    TILE_BODY(0, kt,     4, 1, 1)
    TILE_BODY(1, kt + 1, 4, 1, 1)
    TILE_BODY(2, kt + 2, 4, 1, 1)
    TILE_BODY(3, kt + 3, 4, 1, 1)
  }
  // peel: tiles NTt-4 .. NTt-1 (NTt % 4 == 0)
  TILE_BODY(0, kt,     4, 1, 1)   // stages tile NTt-1
  TILE_BODY(1, kt + 1, 0, 0, 1)
  TILE_BODY(2, kt + 2, 0, 0, 1)
  TILE_BODY(3, kt + 3, 0, 0, 0)

  // epilogue: C/D layout col = lane&15, row = (lane>>4)*4 + j
#pragma unroll
  for (int ni = 0; ni < 4; ++ni) {
    const int col = tn * 256 + wc * 64 + ni * 16 + l15;
    const float bv = bias[col];
#pragma unroll
    for (int mi = 0; mi < 8; ++mi) {
      const int r0 = tm * 256 + wr * 128 + mi * 16 + ((l >> 4) << 2);
      f32x4 v = acc[mi][ni];
#pragma unroll
      for (int j = 0; j < 4; ++j)
        C[(size_t)(r0 + j) * N + col] = v[j] + bv;
    }
  }
#undef STAGE_A
#undef STAGE_B
#undef PF_A03
#undef PF_A47
#undef PF_B
#undef MFMA16
#undef LGKM4
#undef LGKM0
#undef TILE_BODY
}

// ---------------------------------------------------------------------------
extern "C" void kernel_launch(void* const* d_in, const int* in_sizes, int n_in,
                              void* d_out, int out_size, void* d_ws, size_t ws_size,
                              hipStream_t stream) {
  const float* x    = (const float*)d_in[0];
  const float* bias = (const float*)d_in[1];
  const int*   seed = (const int*)d_in[2];
  float* out = (float*)d_out;

  const int K = 4096;                       // IN_FEATURES
  const int N = in_sizes[1];                // OUT_FEATURES (4096)
  const int M = in_sizes[0] / K;            // BATCH*SEQ (8192)

  unsigned short* W  = (unsigned short*)d_ws;
  unsigned short* Xb = W + (size_t)N * K;

  gen_and_cast<<<8192, 256, 0, stream>>>(x, Xb, W, seed, M * K, N * K);

  dim3 grid((M / 256) * (N / 256));
  gemm256<<<grid, 512, 0, stream>>>((const unsigned short*)Xb,
                                    (const unsigned short*)W,
                                    bias, out, M, N, K);
}

// Round 15
// 305.697 us; speedup vs baseline: 12.0979x; 12.0979x over previous
//
#include <hip/hip_runtime.h>
#include <hip/hip_bf16.h>
#include <cstdint>
#include <math.h>

// ---------------------------------------------------------------------------
// GMemLinear: out = (x @ W^T) + bias, W = jax.random.normal(key(seed),[N,K],f64)
// R15: GEMM = R12 exact (proven 226us, MfmaUtil 58%, VGPR 128).
// R13/R14 lesson: divergent per-wave schedule duplication -> structurized
// double-path liveness -> scratch spill (10GB writes, 16x slowdown). Reverted.
// Pre-kernel: every block does BOTH cast and gen slices (grid-stride), no
// role split -> no load imbalance between memory-bound cast & VALU-bound gen.
// ---------------------------------------------------------------------------

typedef __bf16  bf16x8 __attribute__((ext_vector_type(8)));
typedef float   f32x4  __attribute__((ext_vector_type(4)));
typedef unsigned short u16x8 __attribute__((ext_vector_type(8)));

__device__ __forceinline__ unsigned short f2bf_rne(float f) {
  uint32_t x = __float_as_uint(f);
  uint32_t r = (x + 0x7FFFu + ((x >> 16) & 1u)) >> 16;
  return (unsigned short)r;
}

// Threefry-2x32, 20 rounds (Random123 / JAX).
__device__ __forceinline__ void threefry2x32(uint32_t k0, uint32_t k1,
                                             uint32_t x0, uint32_t x1,
                                             uint32_t& o0, uint32_t& o1) {
  uint32_t ks0 = k0, ks1 = k1, ks2 = k0 ^ k1 ^ 0x1BD11BDAu;
  uint32_t ks[3] = {ks0, ks1, ks2};
  x0 += ks0; x1 += ks1;
  const uint32_t rot0[4] = {13u, 15u, 26u, 6u};
  const uint32_t rot1[4] = {17u, 29u, 16u, 24u};
#pragma unroll
  for (int i = 0; i < 5; ++i) {
    const uint32_t* r = (i & 1) ? rot1 : rot0;
#pragma unroll
    for (int j = 0; j < 4; ++j) {
      x0 += x1;
      x1 = (x1 << r[j]) | (x1 >> (32u - r[j]));
      x1 ^= x0;
    }
    x0 += ks[(i + 1) % 3];
    x1 += ks[(i + 2) % 3] + (uint32_t)(i + 1);
  }
  o0 = x0; o1 = x1;
}

__device__ __forceinline__ double erfinv_mixed(double u) {
  double au = fabs(u);
  double t  = (1.0 - au) * (1.0 + au);
  float  wf = -logf((float)t);
  if (wf < 15.5f) {
    float w, p;
    if (wf < 5.0f) {
      w = wf - 2.5f;
      p = 2.81022636e-08f;
      p = 3.43273939e-07f + p * w;
      p = -3.5233877e-06f + p * w;
      p = -4.39150654e-06f + p * w;
      p = 0.00021858087f + p * w;
      p = -0.00125372503f + p * w;
      p = -0.00417768164f + p * w;
      p = 0.246640727f + p * w;
      p = 1.50140941f + p * w;
    } else {
      w = sqrtf(wf) - 3.0f;
      p = -0.000200214257f;
      p = 0.000100950558f + p * w;
      p = 0.00134934322f + p * w;
      p = -0.00367342844f + p * w;
      p = 0.00573950773f + p * w;
      p = -0.0076224613f + p * w;
      p = 0.00943887047f + p * w;
      p = 1.00167406f + p * w;
      p = 2.83297682f + p * w;
    }
    return (double)(p * (float)u);
  } else {
    double L = -log(1.0 - au);
    double r = sqrt(L);
    r = sqrt(L - log(r) - 0.5723649429247001);
    r = sqrt(L - log(r) - 0.5723649429247001);
    return (u < 0.0) ? -r : r;
  }
}

// ---------------------------------------------------------------------------
// Pre-kernel: every block grid-strides its share of BOTH tasks:
// (1) cast x f32->bf16 (memory-bound), (2) regenerate W (VALU-bound).
// ---------------------------------------------------------------------------
__global__ void gen_and_cast(const float* __restrict__ X,
                             unsigned short* __restrict__ Y,
                             unsigned short* __restrict__ W,
                             const int* __restrict__ seedp,
                             int nx, int nw) {
  const int gsz = (int)(gridDim.x * blockDim.x);
  const int gid = (int)(blockIdx.x * blockDim.x + threadIdx.x);

  // phase 1: cast (8 f32 -> 8 bf16 per iter)
  const int n8 = nx >> 3;
  for (int q = gid; q < n8; q += gsz) {
    const float4* p = (const float4*)(X + ((size_t)q << 3));
    float4 a = p[0], b = p[1];
    u16x8 o;
    o[0] = f2bf_rne(a.x); o[1] = f2bf_rne(a.y);
    o[2] = f2bf_rne(a.z); o[3] = f2bf_rne(a.w);
    o[4] = f2bf_rne(b.x); o[5] = f2bf_rne(b.y);
    o[6] = f2bf_rne(b.z); o[7] = f2bf_rne(b.w);
    *(u16x8*)(Y + ((size_t)q << 3)) = o;
  }

  // phase 2: generate W (4 elements per iter)
  const uint32_t k1 = (uint32_t)seedp[0];
  const uint32_t k0 = 0u;
  const double DLO = -0x1.fffffffffffffp-1;   // -(1 - 2^-53)
  const int nq = nw >> 2;
  for (int q = gid; q < nq; q += gsz) {
    ushort4 outv;
    unsigned short tmp[4];
#pragma unroll
    for (int j = 0; j < 4; ++j) {
      uint32_t e = ((uint32_t)q << 2) + (uint32_t)j;
      uint32_t o0, o1;
      threefry2x32(k0, k1, 0u, e, o0, o1);
      uint64_t bits = ((uint64_t)o0 << 32) | (uint64_t)o1;
      uint64_t fb = (bits >> 12) | 0x3FF0000000000000ull;
      union { uint64_t u; double d; } cv; cv.u = fb;
      double f = cv.d - 1.0;
      double u = f * 2.0 + DLO;
      u = fmax(u, DLO);
      double x = erfinv_mixed(u);
      float wv = (float)(1.4142135623730951 * x);
      tmp[j] = f2bf_rne(wv);
    }
    outv.x = tmp[0]; outv.y = tmp[1]; outv.z = tmp[2]; outv.w = tmp[3];
    *(ushort4*)(W + ((size_t)q << 2)) = outv;
  }
}

// ---------------------------------------------------------------------------
// 256x256 GEMM, BK=32, quad-buffer, interleaved split prefetch (R12 exact).
// ---------------------------------------------------------------------------

__device__ __forceinline__ void gload_lds16(const void* g, void* l) {
  __builtin_amdgcn_global_load_lds(
      (const __attribute__((address_space(1))) unsigned int*)g,
      (__attribute__((address_space(3))) unsigned int*)l, 16, 0, 0);
}

__device__ __forceinline__ uint32_t lds_u32(void* p) {
  return (uint32_t)(uintptr_t)(__attribute__((address_space(3))) char*)p;
}

template <int OFF>
__device__ __forceinline__ bf16x8 dsr16(uint32_t a) {
  bf16x8 r;
  asm volatile("ds_read_b128 %0, %1 offset:%2" : "=v"(r) : "v"(a), "i"(OFF));
  return r;
}

__global__ __launch_bounds__(512, 2) void gemm256(
    const unsigned short* __restrict__ A,   // [M][K] bf16
    const unsigned short* __restrict__ B,   // [N][K] bf16
    const float* __restrict__ bias,         // [N]
    float* __restrict__ C,                  // [M][N] f32
    int M, int N, int K) {
  __shared__ __align__(1024) char lds[131072];

  const int nwg = (int)gridDim.x;
  int wg = (int)blockIdx.x;
  wg = (wg & 7) * (nwg >> 3) + (wg >> 3);       // bijective: nwg % 8 == 0
  const int ntn = N >> 8;
  const int tm = wg / ntn, tn = wg - tm * ntn;

  const int tid = (int)threadIdx.x;
  const int w = tid >> 6, l = tid & 63;
  const int wr = w >> 2, wc = w & 3;            // wave grid 2(M) x 4(N)
  const int l15 = l & 15;

  // read-side swizzled lane offset within a 1KiB (16row x 64B) subtile
  int laneRd = (l15 << 6) | ((l >> 4) << 4);
  laneRd ^= ((l15 >> 1) & 3) << 4;
  // stage-side: lane l sources global row l>>2, col-slot pre-inverse-swizzled
  const int stRow = l >> 2;
  const int stCol = (((l & 3) ^ ((l >> 3) & 3)) << 4);

  const char* Ag = (const char*)A;
  const char* Bg = (const char*)B;
  const long rowA0 = (long)tm * 256;
  const long rowB0 = (long)tn * 256;
  const long Kb = (long)K;

  const uint32_t lds0  = lds_u32(&lds[0]);
  const uint32_t aBase = lds0 + (uint32_t)(wr * 8192 + laneRd);
  const uint32_t bBase = lds0 + 16384u + (uint32_t)(wc * 4096 + laneRd);

#define STAGE_A(kt_, cs_)                                                     \
  _Pragma("unroll")                                                           \
  for (int i_ = 0; i_ < 2; ++i_) {                                            \
    const int u_ = w * 2 + i_;                                                \
    gload_lds16(Ag + 2 * ((rowA0 + u_ * 16 + stRow) * Kb + (long)(kt_) * 32) + stCol, \
                &lds[(cs_) * 32768 + u_ * 1024]);                             \
  }
#define STAGE_B(kt_, cs_)                                                     \
  _Pragma("unroll")                                                           \
  for (int i_ = 0; i_ < 2; ++i_) {                                            \
    const int u_ = w * 2 + i_;                                                \
    gload_lds16(Bg + 2 * ((rowB0 + u_ * 16 + stRow) * Kb + (long)(kt_) * 32) + stCol, \
                &lds[(cs_) * 32768 + 16384 + u_ * 1024]);                     \
  }

#define PF_A03(cn_)                                                           \
  {                                                                           \
    const uint32_t aB = aBase + (cn_) * 32768u;                               \
    aq[0] = dsr16<0>(aB);    aq[1] = dsr16<1024>(aB);                         \
    aq[2] = dsr16<2048>(aB); aq[3] = dsr16<3072>(aB);                         \
  }
#define PF_REST(cn_)                                                          \
  {                                                                           \
    const uint32_t aB = aBase + (cn_) * 32768u;                               \
    const uint32_t bB = bBase + (cn_) * 32768u;                               \
    bq[0] = dsr16<0>(bB);    bq[1] = dsr16<1024>(bB);                         \
    bq[2] = dsr16<2048>(bB); bq[3] = dsr16<3072>(bB);                         \
    aq[4] = dsr16<4096>(aB); aq[5] = dsr16<5120>(aB);                         \
    aq[6] = dsr16<6144>(aB); aq[7] = dsr16<7168>(aB);                         \
  }

#define MFMA16(base_)                                                         \
  _Pragma("unroll")                                                           \
  for (int mi = 0; mi < 4; ++mi)                                              \
    _Pragma("unroll")                                                         \
    for (int ni = 0; ni < 4; ++ni)                                            \
      acc[(base_) + mi][ni] = __builtin_amdgcn_mfma_f32_16x16x32_bf16(        \
          aq[(base_) + mi], bq[ni], acc[(base_) + mi][ni], 0, 0, 0);

#define TILE_BODY(c_, kt_, vm_, st_, pf_)                                     \
  {                                                                           \
    asm volatile("s_waitcnt lgkmcnt(4)" ::: "memory");                        \
    __builtin_amdgcn_sched_barrier(0);                                        \
    __builtin_amdgcn_s_setprio(1);                                            \
    MFMA16(0)                                                                 \
    __builtin_amdgcn_s_setprio(0);                                            \
    if (pf_) { PF_A03(((c_) + 1) & 3) }                                       \
    if (st_) { STAGE_A((kt_) + 3, ((c_) + 3) & 3) }                           \
    if (pf_) { asm volatile("s_waitcnt lgkmcnt(4)" ::: "memory"); }           \
    else     { asm volatile("s_waitcnt lgkmcnt(0)" ::: "memory"); }           \
    __builtin_amdgcn_sched_barrier(0);                                        \
    __builtin_amdgcn_s_setprio(1);                                            \
    MFMA16(4)                                                                 \
    __builtin_amdgcn_s_setprio(0);                                            \
    if (pf_) { PF_REST(((c_) + 1) & 3) }                                      \
    if (st_) { STAGE_B((kt_) + 3, ((c_) + 3) & 3) }                           \
    asm volatile("s_waitcnt vmcnt(" #vm_ ")" ::: "memory");                   \
    __builtin_amdgcn_sched_barrier(0);                                        \
    __builtin_amdgcn_s_barrier();                                             \
  }

  f32x4 acc[8][4];
#pragma unroll
  for (int i = 0; i < 8; ++i)
#pragma unroll
    for (int j = 0; j < 4; ++j) acc[i][j] = (f32x4){0.f, 0.f, 0.f, 0.f};

  bf16x8 aq[8], bq[4];

  const int NTt = K >> 5;   // 128 K-tiles of BK=32

  STAGE_A(0, 0) STAGE_B(0, 0)
  STAGE_A(1, 1) STAGE_B(1, 1)
  STAGE_A(2, 2) STAGE_B(2, 2)
  asm volatile("s_waitcnt vmcnt(4)" ::: "memory");
  __builtin_amdgcn_sched_barrier(0);
  __builtin_amdgcn_s_barrier();
  PF_A03(0)
  PF_REST(0)

  int kt = 0;
  for (; kt + 7 < NTt; kt += 4) {
    TILE_BODY(0, kt,     4, 1, 1)
    TILE_BODY(1, kt + 1, 4, 1, 1)
    TILE_BODY(2, kt + 2, 4, 1, 1)
    TILE_BODY(3, kt + 3, 4, 1, 1)
  }
  TILE_BODY(0, kt,     4, 1, 1)   // stages tile NTt-1
  TILE_BODY(1, kt + 1, 0, 0, 1)
  TILE_BODY(2, kt + 2, 0, 0, 1)
  TILE_BODY(3, kt + 3, 0, 0, 0)

  // epilogue: C/D layout col = lane&15, row = (lane>>4)*4 + j
#pragma unroll
  for (int ni = 0; ni < 4; ++ni) {
    const int col = tn * 256 + wc * 64 + ni * 16 + l15;
    const float bv = bias[col];
#pragma unroll
    for (int mi = 0; mi < 8; ++mi) {
      const int r0 = tm * 256 + wr * 128 + mi * 16 + ((l >> 4) << 2);
      f32x4 v = acc[mi][ni];
#pragma unroll
      for (int j = 0; j < 4; ++j)
        C[(size_t)(r0 + j) * N + col] = v[j] + bv;
    }
  }
#undef STAGE_A
#undef STAGE_B
#undef PF_A03
#undef PF_REST
#undef MFMA16
#undef TILE_BODY
}

// ---------------------------------------------------------------------------
extern "C" void kernel_launch(void* const* d_in, const int* in_sizes, int n_in,
                              void* d_out, int out_size, void* d_ws, size_t ws_size,
                              hipStream_t stream) {
  const float* x    = (const float*)d_in[0];
  const float* bias = (const float*)d_in[1];
  const int*   seed = (const int*)d_in[2];
  float* out = (float*)d_out;

  const int K = 4096;                       // IN_FEATURES
  const int N = in_sizes[1];                // OUT_FEATURES (4096)
  const int M = in_sizes[0] / K;            // BATCH*SEQ (8192)

  unsigned short* W  = (unsigned short*)d_ws;
  unsigned short* Xb = W + (size_t)N * K;

  gen_and_cast<<<2048, 256, 0, stream>>>(x, Xb, W, seed, M * K, N * K);

  dim3 grid((M / 256) * (N / 256));
  gemm256<<<grid, 512, 0, stream>>>((const unsigned short*)Xb,
                                    (const unsigned short*)W,
                                    bias, out, M, N, K);
}

// Round 16
// 301.339 us; speedup vs baseline: 12.2729x; 1.0145x over previous
//
#include <hip/hip_runtime.h>
#include <hip/hip_bf16.h>
#include <cstdint>
#include <math.h>

// ---------------------------------------------------------------------------
// GMemLinear: out = (x @ W^T) + bias, W = jax.random.normal(key(seed),[N,K],f64)
// R16: GEMM = R15/R12 exact. Pre-kernel: phase-order parity split — odd
// blocks cast->gen, even blocks gen->cast, so memory-bound and VALU-bound
// phases overlap chip-wide instead of running in lockstep sequence.
// ---------------------------------------------------------------------------

typedef __bf16  bf16x8 __attribute__((ext_vector_type(8)));
typedef float   f32x4  __attribute__((ext_vector_type(4)));
typedef unsigned short u16x8 __attribute__((ext_vector_type(8)));

__device__ __forceinline__ unsigned short f2bf_rne(float f) {
  uint32_t x = __float_as_uint(f);
  uint32_t r = (x + 0x7FFFu + ((x >> 16) & 1u)) >> 16;
  return (unsigned short)r;
}

// Threefry-2x32, 20 rounds (Random123 / JAX).
__device__ __forceinline__ void threefry2x32(uint32_t k0, uint32_t k1,
                                             uint32_t x0, uint32_t x1,
                                             uint32_t& o0, uint32_t& o1) {
  uint32_t ks0 = k0, ks1 = k1, ks2 = k0 ^ k1 ^ 0x1BD11BDAu;
  uint32_t ks[3] = {ks0, ks1, ks2};
  x0 += ks0; x1 += ks1;
  const uint32_t rot0[4] = {13u, 15u, 26u, 6u};
  const uint32_t rot1[4] = {17u, 29u, 16u, 24u};
#pragma unroll
  for (int i = 0; i < 5; ++i) {
    const uint32_t* r = (i & 1) ? rot1 : rot0;
#pragma unroll
    for (int j = 0; j < 4; ++j) {
      x0 += x1;
      x1 = (x1 << r[j]) | (x1 >> (32u - r[j]));
      x1 ^= x0;
    }
    x0 += ks[(i + 1) % 3];
    x1 += ks[(i + 2) % 3] + (uint32_t)(i + 1);
  }
  o0 = x0; o1 = x1;
}

__device__ __forceinline__ double erfinv_mixed(double u) {
  double au = fabs(u);
  double t  = (1.0 - au) * (1.0 + au);
  float  wf = -logf((float)t);
  if (wf < 15.5f) {
    float w, p;
    if (wf < 5.0f) {
      w = wf - 2.5f;
      p = 2.81022636e-08f;
      p = 3.43273939e-07f + p * w;
      p = -3.5233877e-06f + p * w;
      p = -4.39150654e-06f + p * w;
      p = 0.00021858087f + p * w;
      p = -0.00125372503f + p * w;
      p = -0.00417768164f + p * w;
      p = 0.246640727f + p * w;
      p = 1.50140941f + p * w;
    } else {
      w = sqrtf(wf) - 3.0f;
      p = -0.000200214257f;
      p = 0.000100950558f + p * w;
      p = 0.00134934322f + p * w;
      p = -0.00367342844f + p * w;
      p = 0.00573950773f + p * w;
      p = -0.0076224613f + p * w;
      p = 0.00943887047f + p * w;
      p = 1.00167406f + p * w;
      p = 2.83297682f + p * w;
    }
    return (double)(p * (float)u);
  } else {
    double L = -log(1.0 - au);
    double r = sqrt(L);
    r = sqrt(L - log(r) - 0.5723649429247001);
    r = sqrt(L - log(r) - 0.5723649429247001);
    return (u < 0.0) ? -r : r;
  }
}

// ---------------------------------------------------------------------------
// Pre-kernel phases as inline functions; each block runs both, order by
// block parity so memory-bound cast and VALU-bound gen overlap chip-wide.
// ---------------------------------------------------------------------------
__device__ __forceinline__ void cast_phase(const float* __restrict__ X,
                                           unsigned short* __restrict__ Y,
                                           int nx, int gid, int gsz) {
  const int n8 = nx >> 3;
  for (int q = gid; q < n8; q += gsz) {
    const float4* p = (const float4*)(X + ((size_t)q << 3));
    float4 a = p[0], b = p[1];
    u16x8 o;
    o[0] = f2bf_rne(a.x); o[1] = f2bf_rne(a.y);
    o[2] = f2bf_rne(a.z); o[3] = f2bf_rne(a.w);
    o[4] = f2bf_rne(b.x); o[5] = f2bf_rne(b.y);
    o[6] = f2bf_rne(b.z); o[7] = f2bf_rne(b.w);
    *(u16x8*)(Y + ((size_t)q << 3)) = o;
  }
}

__device__ __forceinline__ void gen_phase(unsigned short* __restrict__ W,
                                          uint32_t k1, int nw, int gid, int gsz) {
  const uint32_t k0 = 0u;
  const double DLO = -0x1.fffffffffffffp-1;   // -(1 - 2^-53)
  const int nq = nw >> 2;
  for (int q = gid; q < nq; q += gsz) {
    ushort4 outv;
    unsigned short tmp[4];
#pragma unroll
    for (int j = 0; j < 4; ++j) {
      uint32_t e = ((uint32_t)q << 2) + (uint32_t)j;
      uint32_t o0, o1;
      threefry2x32(k0, k1, 0u, e, o0, o1);
      uint64_t bits = ((uint64_t)o0 << 32) | (uint64_t)o1;
      uint64_t fb = (bits >> 12) | 0x3FF0000000000000ull;
      union { uint64_t u; double d; } cv; cv.u = fb;
      double f = cv.d - 1.0;
      double u = f * 2.0 + DLO;
      u = fmax(u, DLO);
      double x = erfinv_mixed(u);
      float wv = (float)(1.4142135623730951 * x);
      tmp[j] = f2bf_rne(wv);
    }
    outv.x = tmp[0]; outv.y = tmp[1]; outv.z = tmp[2]; outv.w = tmp[3];
    *(ushort4*)(W + ((size_t)q << 2)) = outv;
  }
}

__global__ void gen_and_cast(const float* __restrict__ X,
                             unsigned short* __restrict__ Y,
                             unsigned short* __restrict__ W,
                             const int* __restrict__ seedp,
                             int nx, int nw) {
  const int gsz = (int)(gridDim.x * blockDim.x);
  const int gid = (int)(blockIdx.x * blockDim.x + threadIdx.x);
  const uint32_t k1 = (uint32_t)seedp[0];
  if (blockIdx.x & 1) {
    cast_phase(X, Y, nx, gid, gsz);
    gen_phase(W, k1, nw, gid, gsz);
  } else {
    gen_phase(W, k1, nw, gid, gsz);
    cast_phase(X, Y, nx, gid, gsz);
  }
}

// ---------------------------------------------------------------------------
// 256x256 GEMM, BK=32, quad-buffer, interleaved split prefetch (R12 exact).
// ---------------------------------------------------------------------------

__device__ __forceinline__ void gload_lds16(const void* g, void* l) {
  __builtin_amdgcn_global_load_lds(
      (const __attribute__((address_space(1))) unsigned int*)g,
      (__attribute__((address_space(3))) unsigned int*)l, 16, 0, 0);
}

__device__ __forceinline__ uint32_t lds_u32(void* p) {
  return (uint32_t)(uintptr_t)(__attribute__((address_space(3))) char*)p;
}

template <int OFF>
__device__ __forceinline__ bf16x8 dsr16(uint32_t a) {
  bf16x8 r;
  asm volatile("ds_read_b128 %0, %1 offset:%2" : "=v"(r) : "v"(a), "i"(OFF));
  return r;
}

__global__ __launch_bounds__(512, 2) void gemm256(
    const unsigned short* __restrict__ A,   // [M][K] bf16
    const unsigned short* __restrict__ B,   // [N][K] bf16
    const float* __restrict__ bias,         // [N]
    float* __restrict__ C,                  // [M][N] f32
    int M, int N, int K) {
  __shared__ __align__(1024) char lds[131072];

  const int nwg = (int)gridDim.x;
  int wg = (int)blockIdx.x;
  wg = (wg & 7) * (nwg >> 3) + (wg >> 3);       // bijective: nwg % 8 == 0
  const int ntn = N >> 8;
  const int tm = wg / ntn, tn = wg - tm * ntn;

  const int tid = (int)threadIdx.x;
  const int w = tid >> 6, l = tid & 63;
  const int wr = w >> 2, wc = w & 3;            // wave grid 2(M) x 4(N)
  const int l15 = l & 15;

  // read-side swizzled lane offset within a 1KiB (16row x 64B) subtile
  int laneRd = (l15 << 6) | ((l >> 4) << 4);
  laneRd ^= ((l15 >> 1) & 3) << 4;
  // stage-side: lane l sources global row l>>2, col-slot pre-inverse-swizzled
  const int stRow = l >> 2;
  const int stCol = (((l & 3) ^ ((l >> 3) & 3)) << 4);

  const char* Ag = (const char*)A;
  const char* Bg = (const char*)B;
  const long rowA0 = (long)tm * 256;
  const long rowB0 = (long)tn * 256;
  const long Kb = (long)K;

  const uint32_t lds0  = lds_u32(&lds[0]);
  const uint32_t aBase = lds0 + (uint32_t)(wr * 8192 + laneRd);
  const uint32_t bBase = lds0 + 16384u + (uint32_t)(wc * 4096 + laneRd);

#define STAGE_A(kt_, cs_)                                                     \
  _Pragma("unroll")                                                           \
  for (int i_ = 0; i_ < 2; ++i_) {                                            \
    const int u_ = w * 2 + i_;                                                \
    gload_lds16(Ag + 2 * ((rowA0 + u_ * 16 + stRow) * Kb + (long)(kt_) * 32) + stCol, \
                &lds[(cs_) * 32768 + u_ * 1024]);                             \
  }
#define STAGE_B(kt_, cs_)                                                     \
  _Pragma("unroll")                                                           \
  for (int i_ = 0; i_ < 2; ++i_) {                                            \
    const int u_ = w * 2 + i_;                                                \
    gload_lds16(Bg + 2 * ((rowB0 + u_ * 16 + stRow) * Kb + (long)(kt_) * 32) + stCol, \
                &lds[(cs_) * 32768 + 16384 + u_ * 1024]);                     \
  }

#define PF_A03(cn_)                                                           \
  {                                                                           \
    const uint32_t aB = aBase + (cn_) * 32768u;                               \
    aq[0] = dsr16<0>(aB);    aq[1] = dsr16<1024>(aB);                         \
    aq[2] = dsr16<2048>(aB); aq[3] = dsr16<3072>(aB);                         \
  }
#define PF_REST(cn_)                                                          \
  {                                                                           \
    const uint32_t aB = aBase + (cn_) * 32768u;                               \
    const uint32_t bB = bBase + (cn_) * 32768u;                               \
    bq[0] = dsr16<0>(bB);    bq[1] = dsr16<1024>(bB);                         \
    bq[2] = dsr16<2048>(bB); bq[3] = dsr16<3072>(bB);                         \
    aq[4] = dsr16<4096>(aB); aq[5] = dsr16<5120>(aB);                         \
    aq[6] = dsr16<6144>(aB); aq[7] = dsr16<7168>(aB);                         \
  }

#define MFMA16(base_)                                                         \
  _Pragma("unroll")                                                           \
  for (int mi = 0; mi < 4; ++mi)                                              \
    _Pragma("unroll")                                                         \
    for (int ni = 0; ni < 4; ++ni)                                            \
      acc[(base_) + mi][ni] = __builtin_amdgcn_mfma_f32_16x16x32_bf16(        \
          aq[(base_) + mi], bq[ni], acc[(base_) + mi][ni], 0, 0, 0);

#define TILE_BODY(c_, kt_, vm_, st_, pf_)                                     \
  {                                                                           \
    asm volatile("s_waitcnt lgkmcnt(4)" ::: "memory");                        \
    __builtin_amdgcn_sched_barrier(0);                                        \
    __builtin_amdgcn_s_setprio(1);                                            \
    MFMA16(0)                                                                 \
    __builtin_amdgcn_s_setprio(0);                                            \
    if (pf_) { PF_A03(((c_) + 1) & 3) }                                       \
    if (st_) { STAGE_A((kt_) + 3, ((c_) + 3) & 3) }                           \
    if (pf_) { asm volatile("s_waitcnt lgkmcnt(4)" ::: "memory"); }           \
    else     { asm volatile("s_waitcnt lgkmcnt(0)" ::: "memory"); }           \
    __builtin_amdgcn_sched_barrier(0);                                        \
    __builtin_amdgcn_s_setprio(1);                                            \
    MFMA16(4)                                                                 \
    __builtin_amdgcn_s_setprio(0);                                            \
    if (pf_) { PF_REST(((c_) + 1) & 3) }                                      \
    if (st_) { STAGE_B((kt_) + 3, ((c_) + 3) & 3) }                           \
    asm volatile("s_waitcnt vmcnt(" #vm_ ")" ::: "memory");                   \
    __builtin_amdgcn_sched_barrier(0);                                        \
    __builtin_amdgcn_s_barrier();                                             \
  }

  f32x4 acc[8][4];
#pragma unroll
  for (int i = 0; i < 8; ++i)
#pragma unroll
    for (int j = 0; j < 4; ++j) acc[i][j] = (f32x4){0.f, 0.f, 0.f, 0.f};

  bf16x8 aq[8], bq[4];

  const int NTt = K >> 5;   // 128 K-tiles of BK=32

  STAGE_A(0, 0) STAGE_B(0, 0)
  STAGE_A(1, 1) STAGE_B(1, 1)
  STAGE_A(2, 2) STAGE_B(2, 2)
  asm volatile("s_waitcnt vmcnt(4)" ::: "memory");
  __builtin_amdgcn_sched_barrier(0);
  __builtin_amdgcn_s_barrier();
  PF_A03(0)
  PF_REST(0)

  int kt = 0;
  for (; kt + 7 < NTt; kt += 4) {
    TILE_BODY(0, kt,     4, 1, 1)
    TILE_BODY(1, kt + 1, 4, 1, 1)
    TILE_BODY(2, kt + 2, 4, 1, 1)
    TILE_BODY(3, kt + 3, 4, 1, 1)
  }
  TILE_BODY(0, kt,     4, 1, 1)   // stages tile NTt-1
  TILE_BODY(1, kt + 1, 0, 0, 1)
  TILE_BODY(2, kt + 2, 0, 0, 1)
  TILE_BODY(3, kt + 3, 0, 0, 0)

  // epilogue: C/D layout col = lane&15, row = (lane>>4)*4 + j
#pragma unroll
  for (int ni = 0; ni < 4; ++ni) {
    const int col = tn * 256 + wc * 64 + ni * 16 + l15;
    const float bv = bias[col];
#pragma unroll
    for (int mi = 0; mi < 8; ++mi) {
      const int r0 = tm * 256 + wr * 128 + mi * 16 + ((l >> 4) << 2);
      f32x4 v = acc[mi][ni];
#pragma unroll
      for (int j = 0; j < 4; ++j)
        C[(size_t)(r0 + j) * N + col] = v[j] + bv;
    }
  }
#undef STAGE_A
#undef STAGE_B
#undef PF_A03
#undef PF_REST
#undef MFMA16
#undef TILE_BODY
}

// ---------------------------------------------------------------------------
extern "C" void kernel_launch(void* const* d_in, const int* in_sizes, int n_in,
                              void* d_out, int out_size, void* d_ws, size_t ws_size,
                              hipStream_t stream) {
  const float* x    = (const float*)d_in[0];
  const float* bias = (const float*)d_in[1];
  const int*   seed = (const int*)d_in[2];
  float* out = (float*)d_out;

  const int K = 4096;                       // IN_FEATURES
  const int N = in_sizes[1];                // OUT_FEATURES (4096)
  const int M = in_sizes[0] / K;            // BATCH*SEQ (8192)

  unsigned short* W  = (unsigned short*)d_ws;
  unsigned short* Xb = W + (size_t)N * K;

  gen_and_cast<<<2048, 256, 0, stream>>>(x, Xb, W, seed, M * K, N * K);

  dim3 grid((M / 256) * (N / 256));
  gemm256<<<grid, 512, 0, stream>>>((const unsigned short*)Xb,
                                    (const unsigned short*)W,
                                    bias, out, M, N, K);
}

// Round 17
// 300.974 us; speedup vs baseline: 12.2878x; 1.0012x over previous
//
#include <hip/hip_runtime.h>
#include <hip/hip_bf16.h>
#include <cstdint>
#include <math.h>

// ---------------------------------------------------------------------------
// GMemLinear: out = (x @ W^T) + bias, W = jax.random.normal(key(seed),[N,K],f64)
// R17: GEMM = R16/R12 exact (plateau 232us, MfmaUtil ~58%).
// Pre-kernel gen rewritten all-f32 with integer-exact tail:
//   - no u64->f32 converts (R9's mistake): oma built from (u32)(dmin>>27)
//     and (u32)(dmin&m27) via two v_cvt_f32_u32 + one fma;
//   - __logf (v_log_f32) instead of libm logf; zero f64 ops anywhere.
// W perturbation <=1e-3 << bf16 quantization; tail (wf>=15.5, ~3 samples
// in 16.7M) f32 asymptotic, abs err ~1e-4.
// ---------------------------------------------------------------------------

typedef __bf16  bf16x8 __attribute__((ext_vector_type(8)));
typedef float   f32x4  __attribute__((ext_vector_type(4)));
typedef unsigned short u16x8 __attribute__((ext_vector_type(8)));

__device__ __forceinline__ unsigned short f2bf_rne(float f) {
  uint32_t x = __float_as_uint(f);
  uint32_t r = (x + 0x7FFFu + ((x >> 16) & 1u)) >> 16;
  return (unsigned short)r;
}

// Threefry-2x32, 20 rounds (Random123 / JAX).
__device__ __forceinline__ void threefry2x32(uint32_t k0, uint32_t k1,
                                             uint32_t x0, uint32_t x1,
                                             uint32_t& o0, uint32_t& o1) {
  uint32_t ks0 = k0, ks1 = k1, ks2 = k0 ^ k1 ^ 0x1BD11BDAu;
  uint32_t ks[3] = {ks0, ks1, ks2};
  x0 += ks0; x1 += ks1;
  const uint32_t rot0[4] = {13u, 15u, 26u, 6u};
  const uint32_t rot1[4] = {17u, 29u, 16u, 24u};
#pragma unroll
  for (int i = 0; i < 5; ++i) {
    const uint32_t* r = (i & 1) ? rot1 : rot0;
#pragma unroll
    for (int j = 0; j < 4; ++j) {
      x0 += x1;
      x1 = (x1 << r[j]) | (x1 >> (32u - r[j]));
      x1 ^= x0;
    }
    x0 += ks[(i + 1) % 3];
    x1 += ks[(i + 2) % 3] + (uint32_t)(i + 1);
  }
  o0 = x0; o1 = x1;
}

// All-f32 normal from the 52-bit mantissa draw (JAX-compatible to ~1e-3).
// m52 = bits>>12; u = m52*2^-51 - 1; oma = 1-|u| built EXACTLY from integers.
__device__ __forceinline__ float normal_from_bits_f32(uint64_t m52) {
  const bool pos = (m52 >> 51) & 1;
  uint64_t dmin = pos ? ((1ull << 52) - m52) : m52;
  uint32_t hi = (uint32_t)(dmin >> 27);
  uint32_t lo = (uint32_t)(dmin & 0x7FFFFFFu);
  float oma = fmaf((float)hi, 0x1p-24f, (float)lo * 0x1p-51f);
  oma = fmaxf(oma, 0x1p-53f);              // ref's DLO clamp (m52 == 0)
  float au  = 1.0f - oma;
  float u   = pos ? au : -au;
  float opa = 2.0f - oma;
  float t   = oma * opa;
  float wf  = -__logf(t);
  float x;
  if (wf < 15.5f) {
    float w, p;
    if (wf < 5.0f) {
      w = wf - 2.5f;
      p = 2.81022636e-08f;
      p = 3.43273939e-07f + p * w;
      p = -3.5233877e-06f + p * w;
      p = -4.39150654e-06f + p * w;
      p = 0.00021858087f + p * w;
      p = -0.00125372503f + p * w;
      p = -0.00417768164f + p * w;
      p = 0.246640727f + p * w;
      p = 1.50140941f + p * w;
    } else {
      w = sqrtf(wf) - 3.0f;
      p = -0.000200214257f;
      p = 0.000100950558f + p * w;
      p = 0.00134934322f + p * w;
      p = -0.00367342844f + p * w;
      p = 0.00573950773f + p * w;
      p = -0.0076224613f + p * w;
      p = 0.00943887047f + p * w;
      p = 1.00167406f + p * w;
      p = 2.83297682f + p * w;
    }
    x = p * u;
  } else {
    float L = wf + __logf(opa);            // -log(1-|u|)
    float r = sqrtf(L);
    r = sqrtf(L - __logf(r) - 0.57236494f);
    r = sqrtf(L - __logf(r) - 0.57236494f);
    x = pos ? r : -r;
  }
  return 1.41421356f * x;
}

// ---------------------------------------------------------------------------
// Pre-kernel phases; each block runs both, order by block parity so the
// memory-bound cast and VALU-bound gen overlap chip-wide.
// ---------------------------------------------------------------------------
__device__ __forceinline__ void cast_phase(const float* __restrict__ X,
                                           unsigned short* __restrict__ Y,
                                           int nx, int gid, int gsz) {
  const int n8 = nx >> 3;
  for (int q = gid; q < n8; q += gsz) {
    const float4* p = (const float4*)(X + ((size_t)q << 3));
    float4 a = p[0], b = p[1];
    u16x8 o;
    o[0] = f2bf_rne(a.x); o[1] = f2bf_rne(a.y);
    o[2] = f2bf_rne(a.z); o[3] = f2bf_rne(a.w);
    o[4] = f2bf_rne(b.x); o[5] = f2bf_rne(b.y);
    o[6] = f2bf_rne(b.z); o[7] = f2bf_rne(b.w);
    *(u16x8*)(Y + ((size_t)q << 3)) = o;
  }
}

__device__ __forceinline__ void gen_phase(unsigned short* __restrict__ W,
                                          uint32_t k1, int nw, int gid, int gsz) {
  const uint32_t k0 = 0u;
  const int nq = nw >> 2;
  for (int q = gid; q < nq; q += gsz) {
    ushort4 outv;
    unsigned short tmp[4];
#pragma unroll
    for (int j = 0; j < 4; ++j) {
      uint32_t e = ((uint32_t)q << 2) + (uint32_t)j;
      uint32_t o0, o1;
      threefry2x32(k0, k1, 0u, e, o0, o1);
      uint64_t bits = ((uint64_t)o0 << 32) | (uint64_t)o1;
      tmp[j] = f2bf_rne(normal_from_bits_f32(bits >> 12));
    }
    outv.x = tmp[0]; outv.y = tmp[1]; outv.z = tmp[2]; outv.w = tmp[3];
    *(ushort4*)(W + ((size_t)q << 2)) = outv;
  }
}

__global__ void gen_and_cast(const float* __restrict__ X,
                             unsigned short* __restrict__ Y,
                             unsigned short* __restrict__ W,
                             const int* __restrict__ seedp,
                             int nx, int nw) {
  const int gsz = (int)(gridDim.x * blockDim.x);
  const int gid = (int)(blockIdx.x * blockDim.x + threadIdx.x);
  const uint32_t k1 = (uint32_t)seedp[0];
  if (blockIdx.x & 1) {
    cast_phase(X, Y, nx, gid, gsz);
    gen_phase(W, k1, nw, gid, gsz);
  } else {
    gen_phase(W, k1, nw, gid, gsz);
    cast_phase(X, Y, nx, gid, gsz);
  }
}

// ---------------------------------------------------------------------------
// 256x256 GEMM, BK=32, quad-buffer, interleaved split prefetch (R12 exact).
// ---------------------------------------------------------------------------

__device__ __forceinline__ void gload_lds16(const void* g, void* l) {
  __builtin_amdgcn_global_load_lds(
      (const __attribute__((address_space(1))) unsigned int*)g,
      (__attribute__((address_space(3))) unsigned int*)l, 16, 0, 0);
}

__device__ __forceinline__ uint32_t lds_u32(void* p) {
  return (uint32_t)(uintptr_t)(__attribute__((address_space(3))) char*)p;
}

template <int OFF>
__device__ __forceinline__ bf16x8 dsr16(uint32_t a) {
  bf16x8 r;
  asm volatile("ds_read_b128 %0, %1 offset:%2" : "=v"(r) : "v"(a), "i"(OFF));
  return r;
}

__global__ __launch_bounds__(512, 2) void gemm256(
    const unsigned short* __restrict__ A,   // [M][K] bf16
    const unsigned short* __restrict__ B,   // [N][K] bf16
    const float* __restrict__ bias,         // [N]
    float* __restrict__ C,                  // [M][N] f32
    int M, int N, int K) {
  __shared__ __align__(1024) char lds[131072];

  const int nwg = (int)gridDim.x;
  int wg = (int)blockIdx.x;
  wg = (wg & 7) * (nwg >> 3) + (wg >> 3);       // bijective: nwg % 8 == 0
  const int ntn = N >> 8;
  const int tm = wg / ntn, tn = wg - tm * ntn;

  const int tid = (int)threadIdx.x;
  const int w = tid >> 6, l = tid & 63;
  const int wr = w >> 2, wc = w & 3;            // wave grid 2(M) x 4(N)
  const int l15 = l & 15;

  // read-side swizzled lane offset within a 1KiB (16row x 64B) subtile
  int laneRd = (l15 << 6) | ((l >> 4) << 4);
  laneRd ^= ((l15 >> 1) & 3) << 4;
  // stage-side: lane l sources global row l>>2, col-slot pre-inverse-swizzled
  const int stRow = l >> 2;
  const int stCol = (((l & 3) ^ ((l >> 3) & 3)) << 4);

  const char* Ag = (const char*)A;
  const char* Bg = (const char*)B;
  const long rowA0 = (long)tm * 256;
  const long rowB0 = (long)tn * 256;
  const long Kb = (long)K;

  const uint32_t lds0  = lds_u32(&lds[0]);
  const uint32_t aBase = lds0 + (uint32_t)(wr * 8192 + laneRd);
  const uint32_t bBase = lds0 + 16384u + (uint32_t)(wc * 4096 + laneRd);

#define STAGE_A(kt_, cs_)                                                     \
  _Pragma("unroll")                                                           \
  for (int i_ = 0; i_ < 2; ++i_) {                                            \
    const int u_ = w * 2 + i_;                                                \
    gload_lds16(Ag + 2 * ((rowA0 + u_ * 16 + stRow) * Kb + (long)(kt_) * 32) + stCol, \
                &lds[(cs_) * 32768 + u_ * 1024]);                             \
  }
#define STAGE_B(kt_, cs_)                                                     \
  _Pragma("unroll")                                                           \
  for (int i_ = 0; i_ < 2; ++i_) {                                            \
    const int u_ = w * 2 + i_;                                                \
    gload_lds16(Bg + 2 * ((rowB0 + u_ * 16 + stRow) * Kb + (long)(kt_) * 32) + stCol, \
                &lds[(cs_) * 32768 + 16384 + u_ * 1024]);                     \
  }

#define PF_A03(cn_)                                                           \
  {                                                                           \
    const uint32_t aB = aBase + (cn_) * 32768u;                               \
    aq[0] = dsr16<0>(aB);    aq[1] = dsr16<1024>(aB);                         \
    aq[2] = dsr16<2048>(aB); aq[3] = dsr16<3072>(aB);                         \
  }
#define PF_REST(cn_)                                                          \
  {                                                                           \
    const uint32_t aB = aBase + (cn_) * 32768u;                               \
    const uint32_t bB = bBase + (cn_) * 32768u;                               \
    bq[0] = dsr16<0>(bB);    bq[1] = dsr16<1024>(bB);                         \
    bq[2] = dsr16<2048>(bB); bq[3] = dsr16<3072>(bB);                         \
    aq[4] = dsr16<4096>(aB); aq[5] = dsr16<5120>(aB);                         \
    aq[6] = dsr16<6144>(aB); aq[7] = dsr16<7168>(aB);                         \
  }

#define MFMA16(base_)                                                         \
  _Pragma("unroll")                                                           \
  for (int mi = 0; mi < 4; ++mi)                                              \
    _Pragma("unroll")                                                         \
    for (int ni = 0; ni < 4; ++ni)                                            \
      acc[(base_) + mi][ni] = __builtin_amdgcn_mfma_f32_16x16x32_bf16(        \
          aq[(base_) + mi], bq[ni], acc[(base_) + mi][ni], 0, 0, 0);

#define TILE_BODY(c_, kt_, vm_, st_, pf_)                                     \
  {                                                                           \
    asm volatile("s_waitcnt lgkmcnt(4)" ::: "memory");                        \
    __builtin_amdgcn_sched_barrier(0);                                        \
    __builtin_amdgcn_s_setprio(1);                                            \
    MFMA16(0)                                                                 \
    __builtin_amdgcn_s_setprio(0);                                            \
    if (pf_) { PF_A03(((c_) + 1) & 3) }                                       \
    if (st_) { STAGE_A((kt_) + 3, ((c_) + 3) & 3) }                           \
    if (pf_) { asm volatile("s_waitcnt lgkmcnt(4)" ::: "memory"); }           \
    else     { asm volatile("s_waitcnt lgkmcnt(0)" ::: "memory"); }           \
    __builtin_amdgcn_sched_barrier(0);                                        \
    __builtin_amdgcn_s_setprio(1);                                            \
    MFMA16(4)                                                                 \
    __builtin_amdgcn_s_setprio(0);                                            \
    if (pf_) { PF_REST(((c_) + 1) & 3) }                                      \
    if (st_) { STAGE_B((kt_) + 3, ((c_) + 3) & 3) }                           \
    asm volatile("s_waitcnt vmcnt(" #vm_ ")" ::: "memory");                   \
    __builtin_amdgcn_sched_barrier(0);                                        \
    __builtin_amdgcn_s_barrier();                                             \
  }

  f32x4 acc[8][4];
#pragma unroll
  for (int i = 0; i < 8; ++i)
#pragma unroll
    for (int j = 0; j < 4; ++j) acc[i][j] = (f32x4){0.f, 0.f, 0.f, 0.f};

  bf16x8 aq[8], bq[4];

  const int NTt = K >> 5;   // 128 K-tiles of BK=32

  STAGE_A(0, 0) STAGE_B(0, 0)
  STAGE_A(1, 1) STAGE_B(1, 1)
  STAGE_A(2, 2) STAGE_B(2, 2)
  asm volatile("s_waitcnt vmcnt(4)" ::: "memory");
  __builtin_amdgcn_sched_barrier(0);
  __builtin_amdgcn_s_barrier();
  PF_A03(0)
  PF_REST(0)

  int kt = 0;
  for (; kt + 7 < NTt; kt += 4) {
    TILE_BODY(0, kt,     4, 1, 1)
    TILE_BODY(1, kt + 1, 4, 1, 1)
    TILE_BODY(2, kt + 2, 4, 1, 1)
    TILE_BODY(3, kt + 3, 4, 1, 1)
  }
  TILE_BODY(0, kt,     4, 1, 1)   // stages tile NTt-1
  TILE_BODY(1, kt + 1, 0, 0, 1)
  TILE_BODY(2, kt + 2, 0, 0, 1)
  TILE_BODY(3, kt + 3, 0, 0, 0)

  // epilogue: C/D layout col = lane&15, row = (lane>>4)*4 + j
#pragma unroll
  for (int ni = 0; ni < 4; ++ni) {
    const int col = tn * 256 + wc * 64 + ni * 16 + l15;
    const float bv = bias[col];
#pragma unroll
    for (int mi = 0; mi < 8; ++mi) {
      const int r0 = tm * 256 + wr * 128 + mi * 16 + ((l >> 4) << 2);
      f32x4 v = acc[mi][ni];
#pragma unroll
      for (int j = 0; j < 4; ++j)
        C[(size_t)(r0 + j) * N + col] = v[j] + bv;
    }
  }
#undef STAGE_A
#undef STAGE_B
#undef PF_A03
#undef PF_REST
#undef MFMA16
#undef TILE_BODY
}

// ---------------------------------------------------------------------------
extern "C" void kernel_launch(void* const* d_in, const int* in_sizes, int n_in,
                              void* d_out, int out_size, void* d_ws, size_t ws_size,
                              hipStream_t stream) {
  const float* x    = (const float*)d_in[0];
  const float* bias = (const float*)d_in[1];
  const int*   seed = (const int*)d_in[2];
  float* out = (float*)d_out;

  const int K = 4096;                       // IN_FEATURES
  const int N = in_sizes[1];                // OUT_FEATURES (4096)
  const int M = in_sizes[0] / K;            // BATCH*SEQ (8192)

  unsigned short* W  = (unsigned short*)d_ws;
  unsigned short* Xb = W + (size_t)N * K;

  gen_and_cast<<<2048, 256, 0, stream>>>(x, Xb, W, seed, M * K, N * K);

  dim3 grid((M / 256) * (N / 256));
  gemm256<<<grid, 512, 0, stream>>>((const unsigned short*)Xb,
                                    (const unsigned short*)W,
                                    bias, out, M, N, K);
}

// Round 18
// 297.359 us; speedup vs baseline: 12.4372x; 1.0122x over previous
//
#include <hip/hip_runtime.h>
#include <hip/hip_bf16.h>
#include <cstdint>
#include <math.h>

// ---------------------------------------------------------------------------
// GMemLinear: out = (x @ W^T) + bias, W = jax.random.normal(key(seed),[N,K],f64)
// R18: GEMM rebuilt as the m201-style 8-phase BK=64 double-buffer schedule,
// with a fully derived staging ledger:
//   buffers fixed by phase (buf0 = even tile, buf1 = odd tile);
//   per phase: {ds_reads; stage 1 half-tile; [P4/P8 vmcnt(4)]; barrier;
//              lgkm(0); setprio; 16 MFMA (C-quadrant x K=64); setprio; barrier}
//   stage slots: P1/P2 A(2k+1)->buf1.A, P3/P4 B(2k+2)->buf0.B,
//                P5/P6 A(2k+2)->buf0.A, P7/P8 B(2k+3)->buf1.B
//   vmcnt(4)@P4 retires {B(2k+1),A(2k+1)} (P5's inputs);
//   vmcnt(4)@P8 retires {B(2k+2),A(2k+2)} (next P1's inputs).
// Subtile staging/read swizzle pair identical to the R12-proven one.
// Pre-kernel = R17 (best measured).
// ---------------------------------------------------------------------------

typedef __bf16  bf16x8 __attribute__((ext_vector_type(8)));
typedef float   f32x4  __attribute__((ext_vector_type(4)));
typedef unsigned short u16x8 __attribute__((ext_vector_type(8)));

__device__ __forceinline__ unsigned short f2bf_rne(float f) {
  uint32_t x = __float_as_uint(f);
  uint32_t r = (x + 0x7FFFu + ((x >> 16) & 1u)) >> 16;
  return (unsigned short)r;
}

// Threefry-2x32, 20 rounds (Random123 / JAX).
__device__ __forceinline__ void threefry2x32(uint32_t k0, uint32_t k1,
                                             uint32_t x0, uint32_t x1,
                                             uint32_t& o0, uint32_t& o1) {
  uint32_t ks0 = k0, ks1 = k1, ks2 = k0 ^ k1 ^ 0x1BD11BDAu;
  uint32_t ks[3] = {ks0, ks1, ks2};
  x0 += ks0; x1 += ks1;
  const uint32_t rot0[4] = {13u, 15u, 26u, 6u};
  const uint32_t rot1[4] = {17u, 29u, 16u, 24u};
#pragma unroll
  for (int i = 0; i < 5; ++i) {
    const uint32_t* r = (i & 1) ? rot1 : rot0;
#pragma unroll
    for (int j = 0; j < 4; ++j) {
      x0 += x1;
      x1 = (x1 << r[j]) | (x1 >> (32u - r[j]));
      x1 ^= x0;
    }
    x0 += ks[(i + 1) % 3];
    x1 += ks[(i + 2) % 3] + (uint32_t)(i + 1);
  }
  o0 = x0; o1 = x1;
}

// All-f32 normal from the 52-bit mantissa draw (JAX-compatible to ~1e-3).
__device__ __forceinline__ float normal_from_bits_f32(uint64_t m52) {
  const bool pos = (m52 >> 51) & 1;
  uint64_t dmin = pos ? ((1ull << 52) - m52) : m52;
  uint32_t hi = (uint32_t)(dmin >> 27);
  uint32_t lo = (uint32_t)(dmin & 0x7FFFFFFu);
  float oma = fmaf((float)hi, 0x1p-24f, (float)lo * 0x1p-51f);
  oma = fmaxf(oma, 0x1p-53f);
  float au  = 1.0f - oma;
  float u   = pos ? au : -au;
  float opa = 2.0f - oma;
  float t   = oma * opa;
  float wf  = -__logf(t);
  float x;
  if (wf < 15.5f) {
    float w, p;
    if (wf < 5.0f) {
      w = wf - 2.5f;
      p = 2.81022636e-08f;
      p = 3.43273939e-07f + p * w;
      p = -3.5233877e-06f + p * w;
      p = -4.39150654e-06f + p * w;
      p = 0.00021858087f + p * w;
      p = -0.00125372503f + p * w;
      p = -0.00417768164f + p * w;
      p = 0.246640727f + p * w;
      p = 1.50140941f + p * w;
    } else {
      w = sqrtf(wf) - 3.0f;
      p = -0.000200214257f;
      p = 0.000100950558f + p * w;
      p = 0.00134934322f + p * w;
      p = -0.00367342844f + p * w;
      p = 0.00573950773f + p * w;
      p = -0.0076224613f + p * w;
      p = 0.00943887047f + p * w;
      p = 1.00167406f + p * w;
      p = 2.83297682f + p * w;
    }
    x = p * u;
  } else {
    float L = wf + __logf(opa);
    float r = sqrtf(L);
    r = sqrtf(L - __logf(r) - 0.57236494f);
    r = sqrtf(L - __logf(r) - 0.57236494f);
    x = pos ? r : -r;
  }
  return 1.41421356f * x;
}

__device__ __forceinline__ void cast_phase(const float* __restrict__ X,
                                           unsigned short* __restrict__ Y,
                                           int nx, int gid, int gsz) {
  const int n8 = nx >> 3;
  for (int q = gid; q < n8; q += gsz) {
    const float4* p = (const float4*)(X + ((size_t)q << 3));
    float4 a = p[0], b = p[1];
    u16x8 o;
    o[0] = f2bf_rne(a.x); o[1] = f2bf_rne(a.y);
    o[2] = f2bf_rne(a.z); o[3] = f2bf_rne(a.w);
    o[4] = f2bf_rne(b.x); o[5] = f2bf_rne(b.y);
    o[6] = f2bf_rne(b.z); o[7] = f2bf_rne(b.w);
    *(u16x8*)(Y + ((size_t)q << 3)) = o;
  }
}

__device__ __forceinline__ void gen_phase(unsigned short* __restrict__ W,
                                          uint32_t k1, int nw, int gid, int gsz) {
  const uint32_t k0 = 0u;
  const int nq = nw >> 2;
  for (int q = gid; q < nq; q += gsz) {
    ushort4 outv;
    unsigned short tmp[4];
#pragma unroll
    for (int j = 0; j < 4; ++j) {
      uint32_t e = ((uint32_t)q << 2) + (uint32_t)j;
      uint32_t o0, o1;
      threefry2x32(k0, k1, 0u, e, o0, o1);
      uint64_t bits = ((uint64_t)o0 << 32) | (uint64_t)o1;
      tmp[j] = f2bf_rne(normal_from_bits_f32(bits >> 12));
    }
    outv.x = tmp[0]; outv.y = tmp[1]; outv.z = tmp[2]; outv.w = tmp[3];
    *(ushort4*)(W + ((size_t)q << 2)) = outv;
  }
}

__global__ void gen_and_cast(const float* __restrict__ X,
                             unsigned short* __restrict__ Y,
                             unsigned short* __restrict__ W,
                             const int* __restrict__ seedp,
                             int nx, int nw) {
  const int gsz = (int)(gridDim.x * blockDim.x);
  const int gid = (int)(blockIdx.x * blockDim.x + threadIdx.x);
  const uint32_t k1 = (uint32_t)seedp[0];
  if (blockIdx.x & 1) {
    cast_phase(X, Y, nx, gid, gsz);
    gen_phase(W, k1, nw, gid, gsz);
  } else {
    gen_phase(W, k1, nw, gid, gsz);
    cast_phase(X, Y, nx, gid, gsz);
  }
}

// ---------------------------------------------------------------------------
// 256x256 GEMM, BK=64, 8-phase double-buffer.
// LDS: buf0.A [0,32K), buf0.B [32K,64K), buf1.A [64K,96K), buf1.B [96K,128K).
// Subtile (rb,kh): rows rb*16..+15, k kh*32..+31 of the K-tile; 1KB, staged by
// one gload (srow=l>>2, stCol swizzled), read at base+laneRd (proven pair).
// ---------------------------------------------------------------------------

__device__ __forceinline__ void gload_lds16(const void* g, void* l) {
  __builtin_amdgcn_global_load_lds(
      (const __attribute__((address_space(1))) unsigned int*)g,
      (__attribute__((address_space(3))) unsigned int*)l, 16, 0, 0);
}

__device__ __forceinline__ uint32_t lds_u32(void* p) {
  return (uint32_t)(uintptr_t)(__attribute__((address_space(3))) char*)p;
}

template <int OFF>
__device__ __forceinline__ bf16x8 dsr16(uint32_t a) {
  bf16x8 r;
  asm volatile("ds_read_b128 %0, %1 offset:%2" : "=v"(r) : "v"(a), "i"(OFF));
  return r;
}

__global__ __launch_bounds__(512, 2) void gemm256(
    const unsigned short* __restrict__ A,   // [M][K] bf16
    const unsigned short* __restrict__ B,   // [N][K] bf16
    const float* __restrict__ bias,         // [N]
    float* __restrict__ C,                  // [M][N] f32
    int M, int N, int K) {
  __shared__ __align__(1024) char lds[131072];

  const int nwg = (int)gridDim.x;
  int wg = (int)blockIdx.x;
  wg = (wg & 7) * (nwg >> 3) + (wg >> 3);       // bijective: nwg % 8 == 0
  const int ntn = N >> 8;
  const int tm = wg / ntn, tn = wg - tm * ntn;

  const int tid = (int)threadIdx.x;
  const int w = tid >> 6, l = tid & 63;
  const int wr = w >> 2, wc = w & 3;            // wave grid 2(M) x 4(N)
  const int l15 = l & 15;

  // read-side swizzled lane offset within a 1KiB subtile (proven pair)
  int laneRd = (l15 << 6) | ((l >> 4) << 4);
  laneRd ^= ((l15 >> 1) & 3) << 4;
  const int stRow = l >> 2;
  const int stCol = (((l & 3) ^ ((l >> 3) & 3)) << 4);

  const char* Ag = (const char*)A;
  const char* Bg = (const char*)B;
  const long rowA0 = (long)tm * 256;
  const long rowB0 = (long)tn * 256;
  const long Kb = (long)K;

  const uint32_t lds0 = lds_u32(&lds[0]);
  // read bases: wave's A rowblocks start at wr*8 (subtile wr*16), B at wc*4
  const uint32_t bA0r = lds0 + (uint32_t)(wr * 16384 + laneRd);           // buf0.A
  const uint32_t bB0r = lds0 + 32768u + (uint32_t)(wc * 8192 + laneRd);   // buf0.B
  const uint32_t bA1r = bA0r + 65536u;                                    // buf1.A
  const uint32_t bB1r = bB0r + 65536u;                                    // buf1.B

  // stage A half h_ (rowblocks h*8..h*8+7) of K-tile kt_ into buffer at boff_
#define STAGE_AH(kt_, h_, boff_)                                              \
  {                                                                           \
    const int rb_ = (h_) * 8 + w;                                             \
    _Pragma("unroll")                                                         \
    for (int i_ = 0; i_ < 2; ++i_)                                            \
      gload_lds16(Ag + 2 * ((rowA0 + rb_ * 16 + stRow) * Kb +                 \
                            (long)(kt_) * 64 + i_ * 32) + stCol,              \
                  &lds[(boff_) + (rb_ * 2 + i_) * 1024]);                     \
  }
#define STAGE_BH(kt_, h_, boff_)                                              \
  {                                                                           \
    const int cb_ = (h_) * 8 + w;                                             \
    _Pragma("unroll")                                                         \
    for (int i_ = 0; i_ < 2; ++i_)                                            \
      gload_lds16(Bg + 2 * ((rowB0 + cb_ * 16 + stRow) * Kb +                 \
                            (long)(kt_) * 64 + i_ * 32) + stCol,              \
                  &lds[(boff_) + (cb_ * 2 + i_) * 1024]);                     \
  }

#define RD_B(bB_)                                                             \
  bq[0][0] = dsr16<0>(bB_);    bq[0][1] = dsr16<1024>(bB_);                   \
  bq[1][0] = dsr16<2048>(bB_); bq[1][1] = dsr16<3072>(bB_);                   \
  bq[2][0] = dsr16<4096>(bB_); bq[2][1] = dsr16<5120>(bB_);                   \
  bq[3][0] = dsr16<6144>(bB_); bq[3][1] = dsr16<7168>(bB_);

#define RD_A(q_, bA_)                                                         \
  aq[0][0] = dsr16<((q_) * 4 + 0) * 1024>(bA_);                               \
  aq[0][1] = dsr16<((q_) * 4 + 1) * 1024>(bA_);                               \
  aq[1][0] = dsr16<((q_) * 4 + 2) * 1024>(bA_);                               \
  aq[1][1] = dsr16<((q_) * 4 + 3) * 1024>(bA_);

#define MFMAQ(q_)                                                             \
  _Pragma("unroll")                                                           \
  for (int kh = 0; kh < 2; ++kh)                                              \
    _Pragma("unroll")                                                         \
    for (int i = 0; i < 2; ++i)                                               \
      _Pragma("unroll")                                                       \
      for (int ni = 0; ni < 4; ++ni)                                          \
        acc[2 * (q_) + i][ni] = __builtin_amdgcn_mfma_f32_16x16x32_bf16(      \
            aq[i][kh], bq[ni][kh], acc[2 * (q_) + i][ni], 0, 0, 0);

#define VM4 asm volatile("s_waitcnt vmcnt(4)" ::: "memory");                  \
  __builtin_amdgcn_sched_barrier(0);
#define VM0 asm volatile("s_waitcnt vmcnt(0)" ::: "memory");                  \
  __builtin_amdgcn_sched_barrier(0);
#define NOVM

// One phase: reads, stage, optional vmcnt, barrier, lgkm0, MFMA quad, barrier.
#define PH(q_, bA_, bB_, STG, VMW)                                            \
  {                                                                           \
    bf16x8 aq[2][2];                                                          \
    if ((q_) == 0) { RD_B(bB_) }                                              \
    RD_A(q_, bA_)                                                             \
    STG                                                                       \
    VMW                                                                       \
    __builtin_amdgcn_s_barrier();                                             \
    asm volatile("s_waitcnt lgkmcnt(0)" ::: "memory");                        \
    __builtin_amdgcn_sched_barrier(0);                                        \
    __builtin_amdgcn_s_setprio(1);                                            \
    MFMAQ(q_)                                                                 \
    __builtin_amdgcn_s_setprio(0);                                            \
    __builtin_amdgcn_s_barrier();                                             \
  }

  f32x4 acc[8][4];
#pragma unroll
  for (int i = 0; i < 8; ++i)
#pragma unroll
    for (int j = 0; j < 4; ++j) acc[i][j] = (f32x4){0.f, 0.f, 0.f, 0.f};

  bf16x8 bq[4][2];

  const int NTt = K >> 6;   // 64 K-tiles of BK=64

  // prologue: A(0),B(0) then B(1); vmcnt(4) retires A0,B0 (leaves B1); barrier
  STAGE_AH(0, 0, 0)      STAGE_AH(0, 1, 0)
  STAGE_BH(0, 0, 32768)  STAGE_BH(0, 1, 32768)
  STAGE_BH(1, 0, 98304)  STAGE_BH(1, 1, 98304)
  VM4
  __builtin_amdgcn_s_barrier();

  // main loop: iterations process (kt, kt+1); kt = 0,2,...,NTt-4
  for (int kt = 0; kt < NTt - 2; kt += 2) {
    PH(0, bA0r, bB0r, STAGE_AH(kt + 1, 0, 65536), NOVM)
    PH(1, bA0r, bB0r, STAGE_AH(kt + 1, 1, 65536), NOVM)
    PH(2, bA0r, bB0r, STAGE_BH(kt + 2, 0, 32768), NOVM)
    PH(3, bA0r, bB0r, STAGE_BH(kt + 2, 1, 32768), VM4)
    PH(0, bA1r, bB1r, STAGE_AH(kt + 2, 0, 0), NOVM)
    PH(1, bA1r, bB1r, STAGE_AH(kt + 2, 1, 0), NOVM)
    PH(2, bA1r, bB1r, STAGE_BH(kt + 3, 0, 98304), NOVM)
    PH(3, bA1r, bB1r, STAGE_BH(kt + 3, 1, 98304), VM4)
  }
  // peel: tiles NTt-2 (buf0), NTt-1 (buf1); stage only A(NTt-1)
  PH(0, bA0r, bB0r, STAGE_AH(NTt - 1, 0, 65536), NOVM)
  PH(1, bA0r, bB0r, STAGE_AH(NTt - 1, 1, 65536), NOVM)
  PH(2, bA0r, bB0r, NOVM, NOVM)
  PH(3, bA0r, bB0r, NOVM, VM0)
  PH(0, bA1r, bB1r, NOVM, NOVM)
  PH(1, bA1r, bB1r, NOVM, NOVM)
  PH(2, bA1r, bB1r, NOVM, NOVM)
  PH(3, bA1r, bB1r, NOVM, NOVM)

  // epilogue: C/D layout col = lane&15, row = (lane>>4)*4 + j
#pragma unroll
  for (int ni = 0; ni < 4; ++ni) {
    const int col = tn * 256 + wc * 64 + ni * 16 + l15;
    const float bv = bias[col];
#pragma unroll
    for (int mi = 0; mi < 8; ++mi) {
      const int r0 = tm * 256 + wr * 128 + mi * 16 + ((l >> 4) << 2);
      f32x4 v = acc[mi][ni];
#pragma unroll
      for (int j = 0; j < 4; ++j)
        C[(size_t)(r0 + j) * N + col] = v[j] + bv;
    }
  }
#undef STAGE_AH
#undef STAGE_BH
#undef RD_A
#undef RD_B
#undef MFMAQ
#undef VM4
#undef VM0
#undef NOVM
#undef PH
}

// ---------------------------------------------------------------------------
extern "C" void kernel_launch(void* const* d_in, const int* in_sizes, int n_in,
                              void* d_out, int out_size, void* d_ws, size_t ws_size,
                              hipStream_t stream) {
  const float* x    = (const float*)d_in[0];
  const float* bias = (const float*)d_in[1];
  const int*   seed = (const int*)d_in[2];
  float* out = (float*)d_out;

  const int K = 4096;                       // IN_FEATURES
  const int N = in_sizes[1];                // OUT_FEATURES (4096)
  const int M = in_sizes[0] / K;            // BATCH*SEQ (8192)

  unsigned short* W  = (unsigned short*)d_ws;
  unsigned short* Xb = W + (size_t)N * K;

  gen_and_cast<<<2048, 256, 0, stream>>>(x, Xb, W, seed, M * K, N * K);

  dim3 grid((M / 256) * (N / 256));
  gemm256<<<grid, 512, 0, stream>>>((const unsigned short*)Xb,
                                    (const unsigned short*)W,
                                    bias, out, M, N, K);
}